// Round 6
// baseline (3094.583 us; speedup 1.0000x reference)
//
#include <hip/hip_runtime.h>

// Grid constants (padded 66^3)
#define GD   66
#define GHW  (66*66)
#define GDHW (66*66*66)
#define CI   32
#define CO   32

// Brick decomposition: 4^3 base cells per brick, 16^3 bricks per batch
#define NBIN 8192              // 2 batches * 16^3 bricks
#define HAL  6                 // halo = brick+2 cells per axis
#define HCELLS (HAL*HAL*HAL)   // 216
#define SBSZ (HCELLS*33 + 8)   // stride-33 swizzled LDS accumulator (dwords)

typedef __attribute__((ext_vector_type(8))) short short8;
typedef __attribute__((ext_vector_type(4))) float float4v;

__device__ __forceinline__ void atomAdd(float* p, float v) {
    unsafeAtomicAdd(p, v);   // native global_atomic_add_f32
}

__device__ __forceinline__ unsigned short f2bf(float f) {
    unsigned u = __float_as_uint(f);
    unsigned r = (u + 0x7FFFu + ((u >> 16) & 1u)) >> 16;   // RNE
    return (unsigned short)r;
}

// ---------------- K prep: fp32 [27][32ci][32co] -> bf16 K^T [864 n=o*32+co][32 k=ci] ----------------

__global__ __launch_bounds__(256) void kprep(
    const float* __restrict__ kern, unsigned short* __restrict__ ktb)
{
    int i = blockIdx.x * 256 + threadIdx.x;      // over 864*32
    if (i >= 27648) return;
    int n = i >> 5, k = i & 31;
    int o = n >> 5, co = n & 31;
    ktb[i] = f2bf(kern[o * 1024 + k * 32 + co]);
}

// ---------------- sort phase ----------------

__global__ __launch_bounds__(256) void binhist(
    const float* __restrict__ pos, int* __restrict__ counts, int BN, int N)
{
    int g = blockIdx.x * 256 + threadIdx.x;
    if (g >= BN) return;
    int bx = (int)(pos[3*g+0] * 64.f);
    int by = (int)(pos[3*g+1] * 64.f);
    int bz = (int)(pos[3*g+2] * 64.f);
    int bin = ((g >= N) << 12) | ((bx >> 2) << 8) | ((by >> 2) << 4) | (bz >> 2);
    atomicAdd(counts + bin, 1);
}

__global__ __launch_bounds__(1024) void binscan(
    const int* __restrict__ counts, int* __restrict__ offs, int* __restrict__ cursor)
{
    __shared__ int s[1024];
    const int t = threadIdx.x;
    int loc[8]; int sum = 0;
    #pragma unroll
    for (int j = 0; j < 8; ++j) { loc[j] = sum; sum += counts[t*8 + j]; }
    s[t] = sum; __syncthreads();
    for (int off = 1; off < 1024; off <<= 1) {
        int v = (t >= off) ? s[t - off] : 0;
        __syncthreads();
        s[t] += v;
        __syncthreads();
    }
    int base = (t > 0) ? s[t-1] : 0;
    #pragma unroll
    for (int j = 0; j < 8; ++j) { offs[t*8+j] = base + loc[j]; cursor[t*8+j] = base + loc[j]; }
    if (t == 1023) offs[NBIN] = s[1023];
}

__global__ __launch_bounds__(256) void binscat(
    const float* __restrict__ pos, int* __restrict__ cursor,
    int* __restrict__ sidx, int BN, int N)
{
    int g = blockIdx.x * 256 + threadIdx.x;
    if (g >= BN) return;
    int bx = (int)(pos[3*g+0] * 64.f);
    int by = (int)(pos[3*g+1] * 64.f);
    int bz = (int)(pos[3*g+2] * 64.f);
    int bin = ((g >= N) << 12) | ((bx >> 2) << 8) | ((by >> 2) << 4) | (bz >> 2);
    int dst = atomicAdd(cursor + bin, 1);
    sidx[dst] = g;
}

// ---------------- main phase: MFMA per brick, FULLY self-calibrating ----------------
// Probes (through the identical A/B feed paths as real data) discover:
//  (1) column label of each D register (probe0),
//  (2) kappa: B-fragment position -> A-my-k at the same hardware k (probe1/2, one-hot B),
//  (3) D (row,col) map with kappa-corrected B (probe3).
// Real B fragments are gathered with kappa, so A/B k-pairing is correct under ANY
// consistent hardware fragment layout.

__global__ __launch_bounds__(256) void p2g_mfma(
    const float* __restrict__ x, const float* __restrict__ pos,
    const unsigned short* __restrict__ ktb, const float* __restrict__ bias,
    const int* __restrict__ sidx, const int* __restrict__ offs,
    float* __restrict__ ws)
{
    __shared__ alignas(16) short xs[64 * 40];  // x bf16, row stride 40 shorts (80 B)
    __shared__ float wst[64 * 33];    // per particle: w[0..26], [28]=cellbase bits, [29]=0
    __shared__ float sb[SBSZ];        // halo brick accumulator, stride-33 swizzle
    __shared__ int kmap[32];          // B-fragment position -> A-my-k (ci)

    const int bid = blockIdx.x;
    const int p0 = offs[bid], p1 = offs[bid + 1];
    if (p0 == p1) return;
    const int np = p1 - p0;
    const int batch = bid >> 12;
    const int br  = bid & 4095;
    const int gx0 = ((br >> 8) & 15) * 4;
    const int gy0 = ((br >> 4) & 15) * 4;
    const int gz0 = (br & 15) * 4;

    const int wave = threadIdx.x >> 6;
    const int lane = threadIdx.x & 63;
    const int col  = lane & 15;
    const int quad = lane >> 4;

    for (int e = threadIdx.x; e < SBSZ; e += 256) sb[e] = 0.f;

    // ================= self-calibration =================
    int rowreg[4], colreg[4];
    float bA[4], bB[4];
    {
        // --- stage A = k-labels: A[r][k] = k+1 (same for every row) ---
        for (int e = threadIdx.x; e < 16 * 40; e += 256) {
            int k = e % 40;
            xs[e] = (k < 32) ? (short)f2bf((float)(k + 1)) : (short)0;
        }
        __syncthreads();
        short8 ap = *(const short8*)&xs[col * 40 + quad * 8];  // same path as compute (mt=0)

        // probe0: column labels. Every B position carries col+1.
        short8 b0p;
        #pragma unroll
        for (int j = 0; j < 8; ++j) b0p[j] = (short)f2bf((float)(col + 1));
        float4v d0 = {0.f, 0.f, 0.f, 0.f};
        d0 = __builtin_amdgcn_mfma_f32_16x16x32_bf16(ap, b0p, d0, 0, 0, 0);

        // probe1/2: one-hot B at my-position col (and col+16).
        short8 b1p, b2p;
        #pragma unroll
        for (int j = 0; j < 8; ++j) {
            int p = quad * 8 + j;
            b1p[j] = (p == col)      ? (short)f2bf(1.f) : (short)0;
            b2p[j] = (p == col + 16) ? (short)f2bf(1.f) : (short)0;
        }
        float4v d1 = {0.f, 0.f, 0.f, 0.f}, d2 = {0.f, 0.f, 0.f, 0.f};
        d1 = __builtin_amdgcn_mfma_f32_16x16x32_bf16(ap, b1p, d1, 0, 0, 0);
        d2 = __builtin_amdgcn_mfma_f32_16x16x32_bf16(ap, b2p, d2, 0, 0, 0);

        if (wave == 0) {            // all waves compute identical results
            #pragma unroll
            for (int i = 0; i < 4; ++i) {
                int c = (int)(d0[i] + 0.5f) / 528 - 1;       // sum_{k=0..31}(k+1) = 528
                c = min(max(c, 0), 15);
                int k1 = (int)(d1[i] + 0.5f) - 1;            // kappa(pos=c)
                int k2 = (int)(d2[i] + 0.5f) - 1;            // kappa(pos=16+c)
                kmap[c]      = min(max(k1, 0), 31);
                kmap[c + 16] = min(max(k2, 0), 31);
            }
        }
        __syncthreads();

        // probe3: D (row,col) map using kappa-corrected B: B_eff[0][n]=1, B_eff[1][n]=n.
        for (int e = threadIdx.x; e < 16 * 40; e += 256) xs[e] = 0;
        __syncthreads();
        if (threadIdx.x < 16) {
            int r = threadIdx.x;
            xs[r * 40 + 0] = (short)f2bf(16.f * (float)r);   // A[r][0] = 16r
            xs[r * 40 + 1] = (short)f2bf(1.f);               // A[r][1] = 1
        }
        __syncthreads();
        short8 ap2 = *(const short8*)&xs[col * 40 + quad * 8];
        short8 bp;
        #pragma unroll
        for (int j = 0; j < 8; ++j) {
            int km = kmap[quad * 8 + j];
            bp[j] = (km == 0) ? (short)f2bf(1.f)
                  : (km == 1) ? (short)f2bf((float)col) : (short)0;
        }
        float4v dz = {0.f, 0.f, 0.f, 0.f};
        dz = __builtin_amdgcn_mfma_f32_16x16x32_bf16(ap2, bp, dz, 0, 0, 0);
        #pragma unroll
        for (int i = 0; i < 4; ++i) {
            int v = (int)(dz[i] + 0.5f);                     // exact: 16*row + col
            rowreg[i] = (v >> 4) & 15;
            colreg[i] = v & 15;
            bA[i] = bias[colreg[i]];
            bB[i] = bias[colreg[i] + 16];
        }
        __syncthreads();   // xs free for real staging
    }

    // per-wave K^T fragments, gathered with kappa (held in VGPRs for the whole block)
    short8 bfr[7][2];
    int   wo[7];     // dword offset of w within particle row (29 = dummy zero)
    int   cadd[7];   // halo-cell offset (oi*36 + oj*6 + ok)
    #pragma unroll
    for (int s = 0; s < 7; ++s) {
        int o = wave + 4 * s;
        if (o < 27) {
            wo[s] = o;
            int oi = o / 9, oj = (o / 3) % 3, ok = o % 3;
            cadd[s] = oi * 36 + oj * 6 + ok;
            #pragma unroll
            for (int nt = 0; nt < 2; ++nt) {
                const unsigned short* kr = ktb + (size_t)(o * 32 + nt * 16 + col) * 32;
                #pragma unroll
                for (int j = 0; j < 8; ++j)
                    bfr[s][nt][j] = (short)kr[kmap[quad * 8 + j]];
            }
        } else {
            wo[s] = 29; cadd[s] = 0;
            short8 z = {0,0,0,0,0,0,0,0};
            bfr[s][0] = z; bfr[s][1] = z;
        }
    }

    for (int c0 = 0; c0 < np; c0 += 64) {
        // ---- stage x (256 threads: thread = (particle, quarter-row)) ----
        {
            int p = threadIdx.x >> 2;
            int q = threadIdx.x & 3;
            float f[8];
            if (c0 + p < np) {
                int g = sidx[p0 + c0 + p];
                const float4* xp = (const float4*)(x + (size_t)g * CI + q * 8);
                float4 v0 = xp[0], v1 = xp[1];
                f[0]=v0.x; f[1]=v0.y; f[2]=v0.z; f[3]=v0.w;
                f[4]=v1.x; f[5]=v1.y; f[6]=v1.z; f[7]=v1.w;
            } else {
                #pragma unroll
                for (int i = 0; i < 8; ++i) f[i] = 0.f;
            }
            int4 pk;
            pk.x = f2bf(f[0]) | (f2bf(f[1]) << 16);
            pk.y = f2bf(f[2]) | (f2bf(f[3]) << 16);
            pk.z = f2bf(f[4]) | (f2bf(f[5]) << 16);
            pk.w = f2bf(f[6]) | (f2bf(f[7]) << 16);
            *(int4*)&xs[p * 40 + q * 8] = pk;
        }
        // ---- stage weights + cell (wave 0, lane = particle) ----
        if (threadIdx.x < 64) {
            int p = threadIdx.x;
            float wx[3], wy[3], wz[3]; int cellb = 0;
            if (c0 + p < np) {
                int g = sidx[p0 + c0 + p];
                float px = pos[3*g+0]*64.f, py = pos[3*g+1]*64.f, pz2 = pos[3*g+2]*64.f;
                int bx = (int)px, by = (int)py, bz = (int)pz2;
                float fx = px-bx-0.5f, fy = py-by-0.5f, fz = pz2-bz-0.5f;
                wx[0]=0.5f*(0.5f-fx)*(0.5f-fx); wx[1]=0.75f-fx*fx; wx[2]=0.5f*(0.5f+fx)*(0.5f+fx);
                wy[0]=0.5f*(0.5f-fy)*(0.5f-fy); wy[1]=0.75f-fy*fy; wy[2]=0.5f*(0.5f+fy)*(0.5f+fy);
                wz[0]=0.5f*(0.5f-fz)*(0.5f-fz); wz[1]=0.75f-fz*fz; wz[2]=0.5f*(0.5f+fz)*(0.5f+fz);
                cellb = (bx-gx0)*36 + (by-gy0)*6 + (bz-gz0);
            } else {
                wx[0]=wx[1]=wx[2]=wy[0]=wy[1]=wy[2]=wz[0]=wz[1]=wz[2]=0.f;
            }
            float* wr = wst + p * 33;
            #pragma unroll
            for (int oi = 0; oi < 3; ++oi)
                #pragma unroll
                for (int oj = 0; oj < 3; ++oj) {
                    float wxy = wx[oi] * wy[oj];
                    wr[oi*9 + oj*3 + 0] = wxy * wz[0];
                    wr[oi*9 + oj*3 + 1] = wxy * wz[1];
                    wr[oi*9 + oj*3 + 2] = wxy * wz[2];
                }
            wr[28] = __int_as_float(cellb);
            wr[29] = 0.f;
        }
        __syncthreads();

        // ---- compute: 7 offset-slots x 4 row-tiles x 2 co-tiles ----
        #pragma unroll
        for (int s = 0; s < 7; ++s) {
            #pragma unroll
            for (int mt = 0; mt < 4; ++mt) {
                short8 af = *(const short8*)&xs[(mt*16 + col) * 40 + quad * 8];
                float4v c0v = {bA[0], bA[1], bA[2], bA[3]};
                float4v c1v = {bB[0], bB[1], bB[2], bB[3]};
                c0v = __builtin_amdgcn_mfma_f32_16x16x32_bf16(af, bfr[s][0], c0v, 0, 0, 0);
                c1v = __builtin_amdgcn_mfma_f32_16x16x32_bf16(af, bfr[s][1], c1v, 0, 0, 0);
                #pragma unroll
                for (int i = 0; i < 4; ++i) {
                    int row = mt*16 + rowreg[i];            // probed particle row
                    float w   = wst[row*33 + wo[s]];
                    int  cell = __float_as_int(wst[row*33 + 28]) + cadd[s];
                    float* sp = sb + cell*33 + colreg[i];   // probed co column
                    atomicAdd(sp,      w * c0v[i]);
                    atomicAdd(sp + 16, w * c1v[i]);
                }
            }
        }
        __syncthreads();   // xs/wst reused next chunk; also orders last ds_adds before flush
    }

    // ---- flush halo brick to ws[b][cell][co], coalesced global atomics ----
    for (int e = threadIdx.x; e < HCELLS * 32; e += 256) {
        const int cell = e >> 5, c = e & 31;
        const float v = sb[cell*33 + c];
        if (v != 0.f) {
            const int cz = cell % 6, cy = (cell / 6) % 6, cx = cell / 36;
            atomAdd(ws + ((size_t)batch*GDHW + (size_t)(gx0+cx)*GHW
                          + (size_t)(gy0+cy)*GD + (gz0+cz)) * 32 + c, v);
        }
    }
}

// Transpose ws[b][cell][co] -> out[b][co][cell], tiled 32x32 through LDS.
__global__ __launch_bounds__(256) void transp_kernel(
    const float* __restrict__ ws, float* __restrict__ out)
{
    __shared__ float tile[32][33];
    const int b     = blockIdx.y;
    const int cell0 = blockIdx.x * 32;
    const int n     = min(32, GDHW - cell0);

    const float* src = ws + ((size_t)b*GDHW + cell0)*32;
    for (int e = threadIdx.x; e < n*32; e += 256)
        tile[e>>5][e&31] = src[e];
    __syncthreads();
    for (int e = threadIdx.x; e < 32*32; e += 256) {
        int c  = e >> 5;
        int cl = e & 31;
        if (cl < n)
            out[((size_t)(b*32 + c))*GDHW + cell0 + cl] = tile[cl][c];
    }
}

// ---------------- fallback (round-1 kernel), used only if ws too small ----------------

template<bool CELLCO>
__global__ __launch_bounds__(256) void p2g_kernel(
    const float* __restrict__ x, const float* __restrict__ pos,
    const float* __restrict__ kern, const float* __restrict__ bias,
    float* __restrict__ dst, int N, int nPairs)
{
    __shared__ float kl[9*32*32];
    const int co   = threadIdx.x & 31;
    const int half = threadIdx.x >> 5;
    const float bco = bias[co];
    const int halvesTotal = gridDim.x * 8;

    for (int oi = 0; oi < 3; ++oi) {
        __syncthreads();
        for (int i = threadIdx.x; i < 9*32*32; i += 256)
            kl[i] = kern[oi*(9*32*32) + i];
        __syncthreads();

        for (int pp = blockIdx.x*8 + half; pp < nPairs; pp += halvesTotal) {
            const int g0 = pp*2;
            float xr[2][32];
            #pragma unroll
            for (int p = 0; p < 2; ++p) {
                const float4* xp = (const float4*)(x + (size_t)(g0+p)*CI);
                #pragma unroll
                for (int i = 0; i < 8; ++i) {
                    float4 v = xp[i];
                    xr[p][4*i+0]=v.x; xr[p][4*i+1]=v.y; xr[p][4*i+2]=v.z; xr[p][4*i+3]=v.w;
                }
            }
            float wxo[2], wy[2][3], wz[2][3];
            int cb[2], bsel[2];
            #pragma unroll
            for (int p = 0; p < 2; ++p) {
                const int gp = g0 + p;
                float px = pos[gp*3+0]*64.f, py = pos[gp*3+1]*64.f, pz = pos[gp*3+2]*64.f;
                int bx = (int)px, by = (int)py, bz = (int)pz;
                float fx = px - bx - 0.5f, fy = py - by - 0.5f, fz = pz - bz - 0.5f;
                float a0 = 0.5f*(0.5f-fx)*(0.5f-fx);
                float a1 = 0.75f - fx*fx;
                float a2 = 0.5f*(0.5f+fx)*(0.5f+fx);
                wxo[p] = (oi==0) ? a0 : ((oi==1) ? a1 : a2);
                wy[p][0]=0.5f*(0.5f-fy)*(0.5f-fy); wy[p][1]=0.75f-fy*fy; wy[p][2]=0.5f*(0.5f+fy)*(0.5f+fy);
                wz[p][0]=0.5f*(0.5f-fz)*(0.5f-fz); wz[p][1]=0.75f-fz*fz; wz[p][2]=0.5f*(0.5f+fz)*(0.5f+fz);
                cb[p]   = (bx+oi)*GHW + by*GD + bz;
                bsel[p] = (gp >= N) ? 1 : 0;
            }
            #pragma unroll
            for (int oj = 0; oj < 3; ++oj) {
                #pragma unroll
                for (int ok = 0; ok < 3; ++ok) {
                    const float* kc = kl + (oj*3+ok)*1024;
                    float y0 = bco, y1 = bco;
                    #pragma unroll
                    for (int ci = 0; ci < 32; ++ci) {
                        float kv = kc[ci*32 + co];
                        y0 += xr[0][ci]*kv;
                        y1 += xr[1][ci]*kv;
                    }
                    {
                        int cell = cb[0] + oj*GD + ok;
                        float w  = wxo[0]*wy[0][oj]*wz[0][ok];
                        size_t a = CELLCO ? (((size_t)bsel[0]*GDHW + cell)*32 + (size_t)co)
                                          : (((size_t)(bsel[0]*32 + co))*GDHW + (size_t)cell);
                        atomAdd(dst + a, w*y0);
                    }
                    {
                        int cell = cb[1] + oj*GD + ok;
                        float w  = wxo[1]*wy[1][oj]*wz[1][ok];
                        size_t a = CELLCO ? (((size_t)bsel[1]*GDHW + cell)*32 + (size_t)co)
                                          : (((size_t)(bsel[1]*32 + co))*GDHW + (size_t)cell);
                        atomAdd(dst + a, w*y1);
                    }
                }
            }
        }
    }
}

extern "C" void kernel_launch(void* const* d_in, const int* in_sizes, int n_in,
                              void* d_out, int out_size, void* d_ws, size_t ws_size,
                              hipStream_t stream) {
    const float* x    = (const float*)d_in[0];
    const float* pos  = (const float*)d_in[1];
    const float* kern = (const float*)d_in[2];
    const float* bias = (const float*)d_in[3];
    float* out = (float*)d_out;

    const int N  = in_sizes[0] / (2*CI);
    const int BN = 2*N;

    const size_t GRIDB   = (size_t)2 * GDHW * CO * sizeof(float);  // 73,598,976
    const size_t oCounts = GRIDB;
    const size_t oOffs   = oCounts + 32768;
    const size_t oCur    = oOffs   + 33024;
    const size_t oIdx    = oCur    + 32768;
    const size_t oKT     = (oIdx + (size_t)BN * 4 + 63) & ~(size_t)63;
    const size_t need    = oKT + 55296;

    if (ws_size >= need) {
        char*  w8     = (char*)d_ws;
        float* wsg    = (float*)w8;
        int*   counts = (int*)(w8 + oCounts);
        int*   offs   = (int*)(w8 + oOffs);
        int*   cursor = (int*)(w8 + oCur);
        int*   sidxb  = (int*)(w8 + oIdx);
        unsigned short* ktb = (unsigned short*)(w8 + oKT);

        hipMemsetAsync(counts, 0, 32768, stream);
        hipMemsetAsync(wsg, 0, GRIDB, stream);
        kprep<<<dim3(108), dim3(256), 0, stream>>>(kern, ktb);
        binhist<<<dim3((BN + 255)/256), dim3(256), 0, stream>>>(pos, counts, BN, N);
        binscan<<<dim3(1), dim3(1024), 0, stream>>>(counts, offs, cursor);
        binscat<<<dim3((BN + 255)/256), dim3(256), 0, stream>>>(pos, cursor, sidxb, BN, N);
        p2g_mfma<<<dim3(NBIN), dim3(256), 0, stream>>>(x, pos, ktb, bias, sidxb, offs, wsg);
        transp_kernel<<<dim3((GDHW + 31)/32, 2), dim3(256), 0, stream>>>(wsg, out);
    } else if (ws_size >= GRIDB) {
        float* wsg = (float*)d_ws;
        hipMemsetAsync(wsg, 0, GRIDB, stream);
        p2g_kernel<true><<<dim3(2048), dim3(256), 0, stream>>>(x, pos, kern, bias, wsg, N, (BN+1)/2);
        transp_kernel<<<dim3((GDHW + 31)/32, 2), dim3(256), 0, stream>>>(wsg, out);
    } else {
        hipMemsetAsync(out, 0, (size_t)out_size * sizeof(float), stream);
        p2g_kernel<false><<<dim3(2048), dim3(256), 0, stream>>>(x, pos, kern, bias, out, N, (BN+1)/2);
    }
}